// Round 1
// baseline (174.969 us; speedup 1.0000x reference)
//
#include <hip/hip_runtime.h>

// out[b][j] = x[b][(j - s_b) mod T]
//
// Realignment strategy: the output index j = 4*v is 16B-aligned, and the
// source misalignment a = (j - s) & 3 = (-s) & 3 is UNIFORM per row. Each
// thread issues two aligned, fully-coalesced float4 loads covering the
// 8-float window [i4, i4+8) and selects its 4 outputs with a wave-uniform
// switch on a. The second load is the next lane's first load -> L1 hit,
// so HBM read traffic stays 1x while VMEM instruction count drops from
// 4 strided dwords to 2 coalesced dwordx4 (1 when a == 0).
__global__ void roll_rows_realign(const float* __restrict__ x,
                                  const int* __restrict__ shifts,
                                  float* __restrict__ out,
                                  int T, int T4) {
    const int b = blockIdx.y;
    const int v = blockIdx.x * blockDim.x + threadIdx.x;
    if (v >= T4) return;

    // shifts are in [0, 1000) per the reference; normalize defensively.
    int s = shifts[b] % T;
    if (s < 0) s += T;

    const int j = v * 4;          // output start (16B-aligned)
    int i = j - s;                // source start, arbitrary alignment
    if (i < 0) i += T;            // i in [0, T)

    const int a = i & 3;          // per-row-uniform misalignment in floats
    const int i4 = i - a;         // aligned down; i4 <= T-4, never wraps
    int i4b = i4 + 4;             // second chunk, may wrap
    if (i4b >= T) i4b -= T;

    const float* __restrict__ xr = x + (size_t)b * (size_t)T;
    const float4 A = *reinterpret_cast<const float4*>(xr + i4);

    float4 r;
    if (a == 0) {
        // fully aligned row: single load suffices
        r = A;
    } else {
        const float4 Bv = *reinterpret_cast<const float4*>(xr + i4b);
        switch (a) {  // wave-uniform: no divergence, no scratch
            case 1: r.x = A.y;  r.y = A.z;  r.z = A.w;  r.w = Bv.x; break;
            case 2: r.x = A.z;  r.y = A.w;  r.z = Bv.x; r.w = Bv.y; break;
            default: r.x = A.w; r.y = Bv.x; r.z = Bv.y; r.w = Bv.z; break;
        }
    }

    *reinterpret_cast<float4*>(out + (size_t)b * (size_t)T + j) = r;
}

// Generic scalar fallback (T not divisible by 4).
__global__ void roll_rows_scalar(const float* __restrict__ x,
                                 const int* __restrict__ shifts,
                                 float* __restrict__ out,
                                 int T) {
    const int b = blockIdx.y;
    const int j = blockIdx.x * blockDim.x + threadIdx.x;
    if (j >= T) return;
    int s = shifts[b] % T;
    if (s < 0) s += T;
    int i = j - s;
    if (i < 0) i += T;
    out[(size_t)b * T + j] = x[(size_t)b * T + i];
}

extern "C" void kernel_launch(void* const* d_in, const int* in_sizes, int n_in,
                              void* d_out, int out_size, void* d_ws, size_t ws_size,
                              hipStream_t stream) {
    const float* x = (const float*)d_in[0];
    const int* shifts = (const int*)d_in[1];
    float* out = (float*)d_out;

    const int B = in_sizes[1];
    const int T = in_sizes[0] / B;

    if ((T & 3) == 0) {
        const int T4 = T / 4;
        dim3 block(256);
        dim3 grid((T4 + 255) / 256, B);
        roll_rows_realign<<<grid, block, 0, stream>>>(x, shifts, out, T, T4);
    } else {
        dim3 block(256);
        dim3 grid((T + 255) / 256, B);
        roll_rows_scalar<<<grid, block, 0, stream>>>(x, shifts, out, T);
    }
}